// Round 4
// baseline (494.889 us; speedup 1.0000x reference)
//
#include <hip/hip_runtime.h>
#include <hip/hip_bf16.h>

typedef __bf16 bf16_t;
typedef __bf16 bf16x8 __attribute__((ext_vector_type(8)));
typedef __bf16 bf16x4v __attribute__((ext_vector_type(4)));
typedef float f32x4 __attribute__((ext_vector_type(4)));

static constexpr int Bn = 2, Tn = 2048, Dn = 1024, DFFn = 4096, Hn = 16, HDn = 64, Wn = 512;
static constexpr int Mn = Bn * Tn;  // 4096

#define MFMA16(a, b, c) __builtin_amdgcn_mfma_f32_16x16x32_bf16(a, b, c, 0, 0, 0)

typedef __attribute__((address_space(3))) void lds_void;
typedef const __attribute__((address_space(1))) void gbl_void;

// ---------------------------------------------------------------- cvt f32->bf16
__global__ __launch_bounds__(256) void cvt_f32_bf16_kernel(const float4* __restrict__ src,
                                                           bf16x4v* __restrict__ dst, int n4) {
  int i = blockIdx.x * 256 + threadIdx.x;
  if (i < n4) {
    float4 v = src[i];
    bf16x4v o;
    o[0] = (bf16_t)v.x; o[1] = (bf16_t)v.y; o[2] = (bf16_t)v.z; o[3] = (bf16_t)v.w;
    dst[i] = o;
  }
}

// ---------------------------------------------------------------- block reduce
__device__ __forceinline__ float blockReduceSum(float v, float* sbuf) {
#pragma unroll
  for (int off = 32; off > 0; off >>= 1) v += __shfl_down(v, off, 64);
  int lane = threadIdx.x & 63, wid = threadIdx.x >> 6;
  __syncthreads();
  if (lane == 0) sbuf[wid] = v;
  __syncthreads();
  return sbuf[0] + sbuf[1] + sbuf[2] + sbuf[3];
}

// ---------------------------------------------------------------- RMSNorm (+gate softmax)
template <bool GATE>
__global__ __launch_bounds__(256) void rmsnorm_kernel(const float* __restrict__ x,
                                                      const float* __restrict__ w,
                                                      bf16_t* __restrict__ out,
                                                      const float* __restrict__ gw,
                                                      const float* __restrict__ gb,
                                                      float* __restrict__ gates) {
  __shared__ float sbuf[4];
  int row = blockIdx.x, tid = threadIdx.x;
  const float4* xr = (const float4*)(x + (long)row * Dn);
  float4 v = xr[tid];
  float ss = v.x * v.x + v.y * v.y + v.z * v.z + v.w * v.w;
  ss = blockReduceSum(ss, sbuf);
  float rms = rsqrtf(ss * (1.0f / Dn) + 1e-6f);
  float4 wv = ((const float4*)w)[tid];
  float h0 = v.x * rms * wv.x, h1 = v.y * rms * wv.y;
  float h2 = v.z * rms * wv.z, h3 = v.w * rms * wv.w;
  bf16x4v o;
  o[0] = (bf16_t)h0; o[1] = (bf16_t)h1; o[2] = (bf16_t)h2; o[3] = (bf16_t)h3;
  ((bf16x4v*)(out + (long)row * Dn))[tid] = o;
  if (GATE) {
    float4 g0v = ((const float4*)gw)[tid];
    float4 g2v = ((const float4*)(gw + 2 * Dn))[tid];
    float l0 = h0 * g0v.x + h1 * g0v.y + h2 * g0v.z + h3 * g0v.w;
    float l2 = h0 * g2v.x + h1 * g2v.y + h2 * g2v.z + h3 * g2v.w;
    l0 = blockReduceSum(l0, sbuf);
    l2 = blockReduceSum(l2, sbuf);
    if (tid == 0) {
      l0 += gb[0];
      l2 += gb[2];
      float mx = fmaxf(l0, l2);
      float e0 = __expf(l0 - mx), e2 = __expf(l2 - mx);
      float inv = 1.0f / (e0 + e2);
      gates[2 * row] = e0 * inv;
      gates[2 * row + 1] = e2 * inv;
    }
  }
}

// ---------------------------------------------------------------- GEMM: C[M,N] = A[M,K] @ Wt[N,K]^T
// Staging via global_load_lds width=16 (m97 structure): per (wave,q) chunk the
// LDS dest is wave-uniform base + lane*16B, matching ldst[q]=((w*4+q)*64+lane)*8.
// EPI 0: outb = bf16(acc + bias?)        (qkv, gate+up)
// EPI 2: outf = resid + g0*(acc+bias) + g2*ret   (proj + mix + residual)
// EPI 3: outf = resid + acc              (ffn down + residual)
template <int EPI>
__global__ __launch_bounds__(256) void gemm_kernel(const bf16_t* __restrict__ A,
                                                   const bf16_t* __restrict__ Wt, int K, int N,
                                                   const float* __restrict__ bias,
                                                   bf16_t* __restrict__ outb,
                                                   float* __restrict__ outf,
                                                   const float* __restrict__ gates,
                                                   const float* __restrict__ ret,
                                                   const float* __restrict__ resid) {
  __shared__ bf16_t smem[8192];  // A tile [128][32] then W tile [128][32]
  const int tid = threadIdx.x;
  const int w = tid >> 6, lane = tid & 63;
  const int wr = w >> 1, wc = w & 1;
  const int m0 = blockIdx.y * 128, n0 = blockIdx.x * 128;

  const bf16_t* gsrc[4];
#pragma unroll
  for (int q = 0; q < 4; q++) {
    int e = ((w * 4 + q) * 64 + lane) * 8;  // bf16 element index in 8192-el staging region
    int rr = (e & 4095) >> 5, cc = e & 31;
    gsrc[q] = (e < 4096) ? (A + (long)(m0 + rr) * K + cc) : (Wt + (long)(n0 + rr) * K + cc);
  }
  // wave-uniform LDS chunk bases (1024B per (wave,q) chunk)
  bf16_t* lbase = &smem[(w * 4) * 512];

  f32x4 acc[4][4];
#pragma unroll
  for (int i = 0; i < 4; i++)
#pragma unroll
    for (int j = 0; j < 4; j++) acc[i][j] = (f32x4){0.f, 0.f, 0.f, 0.f};

  const int lr = lane & 15, lc = (lane >> 4) * 8;

  for (int kt = 0; kt < K; kt += 32) {
    if (kt) __syncthreads();  // all waves done reading previous tile
#pragma unroll
    for (int q = 0; q < 4; q++) {
      __builtin_amdgcn_global_load_lds((gbl_void*)(gsrc[q] + kt), (lds_void*)(lbase + q * 512), 16,
                                       0, 0);
    }
    __syncthreads();  // drains vmcnt -> LDS tile ready

    bf16x8 af[4], bfv[4];
#pragma unroll
    for (int i = 0; i < 4; i++) af[i] = *(const bf16x8*)&smem[(wr * 64 + i * 16 + lr) * 32 + lc];
#pragma unroll
    for (int i = 0; i < 4; i++)
      bfv[i] = *(const bf16x8*)&smem[4096 + (wc * 64 + i * 16 + lr) * 32 + lc];
#pragma unroll
    for (int mi = 0; mi < 4; mi++)
#pragma unroll
      for (int ni = 0; ni < 4; ni++) acc[mi][ni] = MFMA16(af[mi], bfv[ni], acc[mi][ni]);
  }

  // epilogue: C/D layout col=lane&15, row=(lane>>4)*4+reg
  const int lrow4 = (lane >> 4) * 4;
#pragma unroll
  for (int mi = 0; mi < 4; mi++) {
#pragma unroll
    for (int rr2 = 0; rr2 < 4; rr2++) {
      int r = m0 + wr * 64 + mi * 16 + lrow4 + rr2;
      float g0 = 0.f, g2 = 0.f;
      const float* retb = nullptr;
      if (EPI == 2) {
        g0 = gates[2 * r];
        g2 = gates[2 * r + 1];
        retb = ret + ((r >> 11) << 10);  // b = r / 2048, row of (B,1024)
      }
#pragma unroll
      for (int ni = 0; ni < 4; ni++) {
        int c = n0 + wc * 64 + ni * 16 + (lane & 15);
        float v = acc[mi][ni][rr2];
        long idx = (long)r * N + c;
        if (EPI == 0) {
          if (bias) v += bias[c];
          outb[idx] = (bf16_t)v;
        } else if (EPI == 2) {
          outf[idx] = resid[idx] + g0 * (v + bias[c]) + g2 * retb[c];
        } else {
          outf[idx] = resid[idx] + v;
        }
      }
    }
  }
}

// ---------------------------------------------------------------- retrieval projection (tiny)
__global__ __launch_bounds__(256) void retproj_kernel(const float* __restrict__ rc,
                                                      const float* __restrict__ rw,
                                                      float* __restrict__ out) {
  int gw = blockIdx.x * 4 + (threadIdx.x >> 6);  // 0..2047
  int lane = threadIdx.x & 63;
  int b = gw >> 10, n = gw & 1023;
  float v = 0.f;
  for (int k = lane; k < Dn; k += 64) v += rc[b * Dn + k] * rw[(long)n * Dn + k];
#pragma unroll
  for (int off = 32; off > 0; off >>= 1) v += __shfl_down(v, off, 64);
  if (lane == 0) out[gw] = v;
}

// ---------------------------------------------------------------- flash sliding-window attention
// qkv: [b][t][3072] bf16 (q|k|v each 1024, head h at h*64). out: [b][t][1024] bf16.
__global__ __launch_bounds__(256) void attn_kernel(const bf16_t* __restrict__ qkv,
                                                   bf16_t* __restrict__ out) {
  __shared__ bf16_t psh[4][512];  // per-wave P tile [16][32]
  const int tid = threadIdx.x, w = tid >> 6, lane = tid & 63;
  const int qb = blockIdx.x, bh = blockIdx.y;
  const int b = bh >> 4, h = bh & 15;
  const int qw0 = qb * 64 + w * 16;
  const bf16_t* base = qkv + (long)b * Tn * 3072 + h * 64;
  const bf16_t* kb = base + Dn;
  const bf16_t* vb = base + 2 * Dn;
  const int lr = lane & 15, lg = lane >> 4;

  bf16x8 aq0 = *(const bf16x8*)(base + (long)(qw0 + lr) * 3072 + lg * 8);
  bf16x8 aq1 = *(const bf16x8*)(base + (long)(qw0 + lr) * 3072 + lg * 8 + 32);

  float m_run[4], l_run[4];
  f32x4 accv[4];
#pragma unroll
  for (int r = 0; r < 4; r++) { m_run[r] = -1e30f; l_run[r] = 0.f; }
#pragma unroll
  for (int c = 0; c < 4; c++) accv[c] = (f32x4){0.f, 0.f, 0.f, 0.f};

  int j_lo = qw0 - (Wn - 1);
  if (j_lo < 0) j_lo = 0;
  j_lo &= ~31;
  const int j_hi = qw0 + 15;

  for (int j0 = j_lo; j0 <= j_hi; j0 += 32) {
    f32x4 s[2];
#pragma unroll
    for (int hh = 0; hh < 2; hh++) {
      const bf16_t* kr = kb + (long)(j0 + hh * 16 + lr) * 3072 + lg * 8;
      bf16x8 k0 = *(const bf16x8*)kr;
      bf16x8 k1 = *(const bf16x8*)(kr + 32);
      f32x4 z = (f32x4){0.f, 0.f, 0.f, 0.f};
      z = MFMA16(aq0, k0, z);
      z = MFMA16(aq1, k1, z);
      s[hh] = z;
    }
    float mt[4];
#pragma unroll
    for (int r = 0; r < 4; r++) {
      int q = qw0 + lg * 4 + r;
      int c0 = j0 + lr, c1 = j0 + 16 + lr;
      float s0 = (q >= c0 && (q - c0) < Wn) ? s[0][r] * 0.125f : -1e30f;
      float s1 = (q >= c1 && (q - c1) < Wn) ? s[1][r] * 0.125f : -1e30f;
      s[0][r] = s0;
      s[1][r] = s1;
      mt[r] = fmaxf(s0, s1);
    }
#pragma unroll
    for (int off = 1; off < 16; off <<= 1)
#pragma unroll
      for (int r = 0; r < 4; r++) mt[r] = fmaxf(mt[r], __shfl_xor(mt[r], off, 64));
    float rs[4];
#pragma unroll
    for (int r = 0; r < 4; r++) {
      float nm = fmaxf(m_run[r], mt[r]);
      float alpha = __expf(m_run[r] - nm);
      m_run[r] = nm;
      float p0 = __expf(s[0][r] - nm);
      float p1 = __expf(s[1][r] - nm);
      psh[w][(lg * 4 + r) * 32 + lr] = (bf16_t)p0;
      psh[w][(lg * 4 + r) * 32 + 16 + lr] = (bf16_t)p1;
      rs[r] = p0 + p1;
      l_run[r] *= alpha;
#pragma unroll
      for (int c = 0; c < 4; c++) accv[c][r] *= alpha;
    }
#pragma unroll
    for (int off = 1; off < 16; off <<= 1)
#pragma unroll
      for (int r = 0; r < 4; r++) rs[r] += __shfl_xor(rs[r], off, 64);
#pragma unroll
    for (int r = 0; r < 4; r++) l_run[r] += rs[r];

    bf16x8 ap = *(const bf16x8*)&psh[w][lr * 32 + lg * 8];
#pragma unroll
    for (int c = 0; c < 4; c++) {
      bf16x8 bv;
#pragma unroll
      for (int jj = 0; jj < 8; jj++) bv[jj] = vb[(long)(j0 + lg * 8 + jj) * 3072 + c * 16 + lr];
      accv[c] = MFMA16(ap, bv, accv[c]);
    }
  }
#pragma unroll
  for (int r = 0; r < 4; r++) {
    float inv = 1.0f / l_run[r];
    long orow = ((long)b * Tn + qw0 + lg * 4 + r) * Dn + h * 64;
#pragma unroll
    for (int c = 0; c < 4; c++) out[orow + c * 16 + lr] = (bf16_t)(accv[c][r] * inv);
  }
}

// ---------------------------------------------------------------- SwiGLU activation
__global__ __launch_bounds__(256) void silu_mul_kernel(const bf16_t* __restrict__ gu,
                                                       bf16_t* __restrict__ act) {
  int m = blockIdx.y;
  int j0 = (blockIdx.x * 256 + threadIdx.x) * 8;
  bf16x8 g = *(const bf16x8*)(gu + (long)m * (2 * DFFn) + j0);
  bf16x8 u = *(const bf16x8*)(gu + (long)m * (2 * DFFn) + DFFn + j0);
  bf16x8 o;
#pragma unroll
  for (int i = 0; i < 8; i++) {
    float gf = (float)g[i], uf = (float)u[i];
    float sf = gf / (1.0f + __expf(-gf));
    o[i] = (bf16_t)(sf * uf);
  }
  *(bf16x8*)(act + (long)m * DFFn + j0) = o;
}

// ---------------------------------------------------------------- launch
extern "C" void kernel_launch(void* const* d_in, const int* in_sizes, int n_in, void* d_out,
                              int out_size, void* d_ws, size_t ws_size, hipStream_t stream) {
  const float* x = (const float*)d_in[0];
  const float* rc = (const float*)d_in[1];
  const float* n1w = (const float*)d_in[2];
  const float* qkv_w = (const float*)d_in[3];
  const float* qkv_b = (const float*)d_in[4];
  const float* proj_w = (const float*)d_in[5];
  const float* proj_b = (const float*)d_in[6];
  const float* gate_w = (const float*)d_in[7];
  const float* gate_b = (const float*)d_in[8];
  const float* ret_w = (const float*)d_in[9];
  const float* n2w = (const float*)d_in[10];
  const float* fgw = (const float*)d_in[11];
  const float* fuw = (const float*)d_in[12];
  const float* fdw = (const float*)d_in[13];
  float* out = (float*)d_out;

  char* ws = (char*)d_ws;
  size_t off = 0;
  auto alloc = [&](size_t bytes) {
    char* p = ws + off;
    off += (bytes + 255) & ~(size_t)255;
    return p;
  };
  bf16_t* wqkv = (bf16_t*)alloc(3072l * 1024 * 2);
  bf16_t* wproj = (bf16_t*)alloc(1024l * 1024 * 2);
  bf16_t* wgup = (bf16_t*)alloc(8192l * 1024 * 2);
  bf16_t* wdown = (bf16_t*)alloc(1024l * 4096 * 2);
  bf16_t* h1 = (bf16_t*)alloc((long)Mn * 1024 * 2);
  bf16_t* h2 = (bf16_t*)alloc((long)Mn * 1024 * 2);
  bf16_t* qkvb = (bf16_t*)alloc((long)Mn * 3072 * 2);
  bf16_t* attnb = (bf16_t*)alloc((long)Mn * 1024 * 2);
  bf16_t* gupo = (bf16_t*)alloc((long)Mn * 8192 * 2);
  bf16_t* actb = (bf16_t*)alloc((long)Mn * 4096 * 2);
  float* gates = (float*)alloc((long)Mn * 2 * 4);
  float* retb = (float*)alloc(2048 * 4);
  float* xmid = (float*)alloc((long)Mn * 1024 * 4);

  // weights -> bf16 (gate & up concatenated into one [8192][1024])
  cvt_f32_bf16_kernel<<<3072, 256, 0, stream>>>((const float4*)qkv_w, (bf16x4v*)wqkv, 786432);
  cvt_f32_bf16_kernel<<<1024, 256, 0, stream>>>((const float4*)proj_w, (bf16x4v*)wproj, 262144);
  cvt_f32_bf16_kernel<<<4096, 256, 0, stream>>>((const float4*)fgw, (bf16x4v*)wgup, 1048576);
  cvt_f32_bf16_kernel<<<4096, 256, 0, stream>>>((const float4*)fuw, (bf16x4v*)(wgup + 4194304),
                                                1048576);
  cvt_f32_bf16_kernel<<<4096, 256, 0, stream>>>((const float4*)fdw, (bf16x4v*)wdown, 1048576);

  rmsnorm_kernel<true><<<Mn, 256, 0, stream>>>(x, n1w, h1, gate_w, gate_b, gates);
  gemm_kernel<0><<<dim3(24, 32), 256, 0, stream>>>(h1, wqkv, 1024, 3072, qkv_b, qkvb, nullptr,
                                                   nullptr, nullptr, nullptr);
  retproj_kernel<<<512, 256, 0, stream>>>(rc, ret_w, retb);
  attn_kernel<<<dim3(32, 32), 256, 0, stream>>>(qkvb, attnb);
  gemm_kernel<2><<<dim3(8, 32), 256, 0, stream>>>(attnb, wproj, 1024, 1024, proj_b, nullptr, xmid,
                                                  gates, retb, x);
  rmsnorm_kernel<false><<<Mn, 256, 0, stream>>>(xmid, n2w, h2, nullptr, nullptr, nullptr);
  gemm_kernel<0><<<dim3(64, 32), 256, 0, stream>>>(h2, wgup, 1024, 8192, nullptr, gupo, nullptr,
                                                   nullptr, nullptr, nullptr);
  silu_mul_kernel<<<dim3(2, 4096), 256, 0, stream>>>(gupo, actb);
  gemm_kernel<3><<<dim3(8, 32), 256, 0, stream>>>(actb, wdown, 4096, 1024, nullptr, nullptr, out,
                                                  nullptr, nullptr, xmid);
}

// Round 6
// 486.544 us; speedup vs baseline: 1.0172x; 1.0172x over previous
//
#include <hip/hip_runtime.h>
#include <hip/hip_bf16.h>

typedef __bf16 bf16_t;
typedef __bf16 bf16x8 __attribute__((ext_vector_type(8)));
typedef __bf16 bf16x4v __attribute__((ext_vector_type(4)));
typedef float f32x4 __attribute__((ext_vector_type(4)));

static constexpr int Bn = 2, Tn = 2048, Dn = 1024, DFFn = 4096, Hn = 16, HDn = 64, Wn = 512;
static constexpr int Mn = Bn * Tn;  // 4096

#define MFMA16(a, b, c) __builtin_amdgcn_mfma_f32_16x16x32_bf16(a, b, c, 0, 0, 0)

typedef __attribute__((address_space(3))) void lds_void;
typedef const __attribute__((address_space(1))) void gbl_void;

// ---------------------------------------------------------------- cvt f32->bf16
__global__ __launch_bounds__(256) void cvt_f32_bf16_kernel(const float4* __restrict__ src,
                                                           bf16x4v* __restrict__ dst, int n4) {
  int i = blockIdx.x * 256 + threadIdx.x;
  if (i < n4) {
    float4 v = src[i];
    bf16x4v o;
    o[0] = (bf16_t)v.x; o[1] = (bf16_t)v.y; o[2] = (bf16_t)v.z; o[3] = (bf16_t)v.w;
    dst[i] = o;
  }
}

// ---------------------------------------------------------------- block reduce
__device__ __forceinline__ float blockReduceSum(float v, float* sbuf) {
#pragma unroll
  for (int off = 32; off > 0; off >>= 1) v += __shfl_down(v, off, 64);
  int lane = threadIdx.x & 63, wid = threadIdx.x >> 6;
  __syncthreads();
  if (lane == 0) sbuf[wid] = v;
  __syncthreads();
  return sbuf[0] + sbuf[1] + sbuf[2] + sbuf[3];
}

// ---------------------------------------------------------------- RMSNorm (+gate softmax)
template <bool GATE>
__global__ __launch_bounds__(256) void rmsnorm_kernel(const float* __restrict__ x,
                                                      const float* __restrict__ w,
                                                      bf16_t* __restrict__ out,
                                                      const float* __restrict__ gw,
                                                      const float* __restrict__ gb,
                                                      float* __restrict__ gates) {
  __shared__ float sbuf[4];
  int row = blockIdx.x, tid = threadIdx.x;
  const float4* xr = (const float4*)(x + (long)row * Dn);
  float4 v = xr[tid];
  float ss = v.x * v.x + v.y * v.y + v.z * v.z + v.w * v.w;
  ss = blockReduceSum(ss, sbuf);
  float rms = rsqrtf(ss * (1.0f / Dn) + 1e-6f);
  float4 wv = ((const float4*)w)[tid];
  float h0 = v.x * rms * wv.x, h1 = v.y * rms * wv.y;
  float h2 = v.z * rms * wv.z, h3 = v.w * rms * wv.w;
  bf16x4v o;
  o[0] = (bf16_t)h0; o[1] = (bf16_t)h1; o[2] = (bf16_t)h2; o[3] = (bf16_t)h3;
  ((bf16x4v*)(out + (long)row * Dn))[tid] = o;
  if (GATE) {
    float4 g0v = ((const float4*)gw)[tid];
    float4 g2v = ((const float4*)(gw + 2 * Dn))[tid];
    float l0 = h0 * g0v.x + h1 * g0v.y + h2 * g0v.z + h3 * g0v.w;
    float l2 = h0 * g2v.x + h1 * g2v.y + h2 * g2v.z + h3 * g2v.w;
    l0 = blockReduceSum(l0, sbuf);
    l2 = blockReduceSum(l2, sbuf);
    if (tid == 0) {
      l0 += gb[0];
      l2 += gb[2];
      float mx = fmaxf(l0, l2);
      float e0 = __expf(l0 - mx), e2 = __expf(l2 - mx);
      float inv = 1.0f / (e0 + e2);
      gates[2 * row] = e0 * inv;
      gates[2 * row + 1] = e2 * inv;
    }
  }
}

// ---------------------------------------------------------------- 256x256 8-phase GEMM
// C[M,N] = A[M,K] @ Wt[N,K]^T, bf16 in, bf16 out (+optional bias).
// 512 thr = 8 waves (2M x 4N). BK=64. LDS 128KB: 2 bufs x (A[256][64] + B[256][64]),
// subtiled [16][2][16][32] with st_16x32 swizzle (byte ^= ((byte>>9)&1)<<5 per 1024B subtile),
// realized as inverse-swizzled GLOBAL source + swizzled ds_read (linear gload_lds dest).
// Schedule per K-tile t (buf c=t&1), phases p=0..3 (mi pair 2p,2p+1):
//   p0: ds_read 8 B-frags + 4 A-frags; stage A(t+1)->c^1 ; bar; lgkm0; 16 MFMA; bar
//   p1: 4 A-frags; stage B(t+2) h0 -> c (B of tile t consumed in p0) ; ...
//   p2: 4 A-frags; stage B(t+2) h1 -> c ; ...
//   p3: 4 A-frags; boundary: vmcnt(4) counted (A(t+1) oldest-4 complete), bar.
__global__ __launch_bounds__(512, 2) void gemm256_kernel(const bf16_t* __restrict__ Ag,
                                                         const bf16_t* __restrict__ Wt, int K,
                                                         int N, const float* __restrict__ bias,
                                                         bf16_t* __restrict__ outb) {
  __shared__ bf16_t lds2[65536];  // 128 KB
  const int tid = threadIdx.x;
  const int wid = tid >> 6, lane = tid & 63;
  const int wr = wid >> 2, wc = wid & 3;
  const int m0 = blockIdx.y * 256, n0 = blockIdx.x * 256;
  const int lr = lane & 15, lg = lane >> 4;
  // swizzled read offset (elements) within a [16][32] subtile pair
  const int lterm = (lr * 32 + lg * 8) ^ (((lr >> 3) & 1) << 4);
  // inverse-swizzled global column offset for staging
  const int colsw = (lane & 3) * 8 ^ (((lane >> 5) & 1) << 4);
  const int NT = K >> 6;

  auto stageA = [&](int buf, int half, int t) {
#pragma unroll
    for (int q = 0; q < 2; q++) {
      int s = q * 8 + wid, s_r = s >> 1, s_c = s & 1;
      const bf16_t* src =
          Ag + (long)(m0 + half * 128 + s_r * 16 + (lane >> 2)) * K + (long)t * 64 + s_c * 32 + colsw;
      bf16_t* dst = &lds2[buf * 32768 + (half * 8 + s_r) * 1024 + s_c * 512];
      __builtin_amdgcn_global_load_lds((gbl_void*)src, (lds_void*)dst, 16, 0, 0);
    }
  };
  auto stageB = [&](int buf, int half, int t) {
#pragma unroll
    for (int q = 0; q < 2; q++) {
      int s = q * 8 + wid, s_r = s >> 1, s_c = s & 1;
      const bf16_t* src =
          Wt + (long)(n0 + half * 128 + s_r * 16 + (lane >> 2)) * K + (long)t * 64 + s_c * 32 + colsw;
      bf16_t* dst = &lds2[buf * 32768 + 16384 + (half * 8 + s_r) * 1024 + s_c * 512];
      __builtin_amdgcn_global_load_lds((gbl_void*)src, (lds_void*)dst, 16, 0, 0);
    }
  };

  f32x4 acc[8][4];
#pragma unroll
  for (int i = 0; i < 8; i++)
#pragma unroll
    for (int j = 0; j < 4; j++) acc[i][j] = (f32x4){0.f, 0.f, 0.f, 0.f};

  // prologue: tile0 (B,A) + tile1 B; counted wait leaves tile1-B in flight
  stageB(0, 0, 0);
  stageB(0, 1, 0);
  stageA(0, 0, 0);
  stageA(0, 1, 0);
  if (NT > 1) {
    stageB(1, 0, 1);
    stageB(1, 1, 1);
    asm volatile("s_waitcnt vmcnt(4)" ::: "memory");
  } else {
    asm volatile("s_waitcnt vmcnt(0)" ::: "memory");
  }
  __builtin_amdgcn_sched_barrier(0);
  __builtin_amdgcn_s_barrier();

#define LDA(mi, ks) (*(const bf16x8*)&lds2[ca + ((wr << 3) + (mi)) * 1024 + (ks)*512 + lterm])
#define LDB(ni, ks) (*(const bf16x8*)&lds2[cb + ((wc << 2) + (ni)) * 1024 + (ks)*512 + lterm])

#define GPHASE(mi0, ...)                                                                  \
  do {                                                                                    \
    bf16x8 a0k0 = LDA(mi0, 0), a0k1 = LDA(mi0, 1);                                        \
    bf16x8 a1k0 = LDA((mi0) + 1, 0), a1k1 = LDA((mi0) + 1, 1);                            \
    __VA_ARGS__;                                                                          \
    __builtin_amdgcn_s_barrier();                                                         \
    asm volatile("s_waitcnt lgkmcnt(0)" ::: "memory");                                    \
    __builtin_amdgcn_sched_barrier(0);                                                    \
    __builtin_amdgcn_s_setprio(1);                                                        \
    _Pragma("unroll") for (int ni = 0; ni < 4; ni++) {                                    \
      acc[mi0][ni] = MFMA16(a0k0, bfr[ni][0], acc[mi0][ni]);                              \
      acc[mi0][ni] = MFMA16(a0k1, bfr[ni][1], acc[mi0][ni]);                              \
      acc[(mi0) + 1][ni] = MFMA16(a1k0, bfr[ni][0], acc[(mi0) + 1][ni]);                  \
      acc[(mi0) + 1][ni] = MFMA16(a1k1, bfr[ni][1], acc[(mi0) + 1][ni]);                  \
    }                                                                                     \
    __builtin_amdgcn_s_setprio(0);                                                        \
    __builtin_amdgcn_s_barrier();                                                         \
  } while (0)

#define GTILE(t, cur)                                                                     \
  do {                                                                                    \
    const int ca = (cur)*32768, cb = ca + 16384;                                          \
    bf16x8 bfr[4][2];                                                                     \
    _Pragma("unroll") for (int ni = 0; ni < 4; ni++) {                                    \
      bfr[ni][0] = LDB(ni, 0);                                                            \
      bfr[ni][1] = LDB(ni, 1);                                                            \
    }                                                                                     \
    GPHASE(0, {                                                                           \
      if ((t) + 1 < NT) {                                                                 \
        stageA(1 - (cur), 0, (t) + 1);                                                    \
        stageA(1 - (cur), 1, (t) + 1);                                                    \
      }                                                                                   \
    });                                                                                   \
    GPHASE(2, {                                                                           \
      if ((t) + 2 < NT) stageB((cur), 0, (t) + 2);                                        \
    });                                                                                   \
    GPHASE(4, {                                                                           \
      if ((t) + 2 < NT) stageB((cur), 1, (t) + 2);                                        \
    });                                                                                   \
    GPHASE(6, {});                                                                        \
    if ((t) + 1 < NT) {                                                                   \
      if ((t) + 2 < NT)                                                                   \
        asm volatile("s_waitcnt vmcnt(4)" ::: "memory");                                  \
      else                                                                                \
        asm volatile("s_waitcnt vmcnt(0)" ::: "memory");                                  \
      __builtin_amdgcn_sched_barrier(0);                                                  \
      __builtin_amdgcn_s_barrier();                                                       \
    }                                                                                     \
  } while (0)

  for (int t = 0; t < NT; t += 2) {
    GTILE(t, 0);
    GTILE(t + 1, 1);
  }

  // epilogue: C/D layout col=lane&15, row=(lane>>4)*4+reg
#pragma unroll
  for (int mi = 0; mi < 8; mi++) {
#pragma unroll
    for (int rr = 0; rr < 4; rr++) {
      long r = m0 + wr * 128 + mi * 16 + lg * 4 + rr;
#pragma unroll
      for (int ni = 0; ni < 4; ni++) {
        int c = n0 + wc * 64 + ni * 16 + lr;
        float v = acc[mi][ni][rr];
        if (bias) v += bias[c];
        outb[r * N + c] = (bf16_t)v;
      }
    }
  }
#undef LDA
#undef LDB
#undef GPHASE
#undef GTILE
}

// ---------------------------------------------------------------- 128x128 GEMM (proj/down)
// EPI 2: outf = resid + g0*(acc+bias) + g2*ret   (proj + mix + residual)
// EPI 3: outf = resid + acc              (ffn down + residual)
template <int EPI>
__global__ __launch_bounds__(256) void gemm_kernel(const bf16_t* __restrict__ A,
                                                   const bf16_t* __restrict__ Wt, int K, int N,
                                                   const float* __restrict__ bias,
                                                   bf16_t* __restrict__ outb,
                                                   float* __restrict__ outf,
                                                   const float* __restrict__ gates,
                                                   const float* __restrict__ ret,
                                                   const float* __restrict__ resid) {
  __shared__ bf16_t smem[8192];  // A tile [128][32] then W tile [128][32]
  const int tid = threadIdx.x;
  const int w = tid >> 6, lane = tid & 63;
  const int wr = w >> 1, wc = w & 1;
  const int m0 = blockIdx.y * 128, n0 = blockIdx.x * 128;

  const bf16_t* gsrc[4];
#pragma unroll
  for (int q = 0; q < 4; q++) {
    int e = ((w * 4 + q) * 64 + lane) * 8;  // bf16 element index in 8192-el staging region
    int rr = (e & 4095) >> 5, cc = e & 31;
    gsrc[q] = (e < 4096) ? (A + (long)(m0 + rr) * K + cc) : (Wt + (long)(n0 + rr) * K + cc);
  }
  bf16_t* lbase = &smem[(w * 4) * 512];

  f32x4 acc[4][4];
#pragma unroll
  for (int i = 0; i < 4; i++)
#pragma unroll
    for (int j = 0; j < 4; j++) acc[i][j] = (f32x4){0.f, 0.f, 0.f, 0.f};

  const int lr = lane & 15, lc = (lane >> 4) * 8;

  for (int kt = 0; kt < K; kt += 32) {
    if (kt) __syncthreads();
#pragma unroll
    for (int q = 0; q < 4; q++) {
      __builtin_amdgcn_global_load_lds((gbl_void*)(gsrc[q] + kt), (lds_void*)(lbase + q * 512), 16,
                                       0, 0);
    }
    __syncthreads();

    bf16x8 af[4], bfv[4];
#pragma unroll
    for (int i = 0; i < 4; i++) af[i] = *(const bf16x8*)&smem[(wr * 64 + i * 16 + lr) * 32 + lc];
#pragma unroll
    for (int i = 0; i < 4; i++)
      bfv[i] = *(const bf16x8*)&smem[4096 + (wc * 64 + i * 16 + lr) * 32 + lc];
#pragma unroll
    for (int mi = 0; mi < 4; mi++)
#pragma unroll
      for (int ni = 0; ni < 4; ni++) acc[mi][ni] = MFMA16(af[mi], bfv[ni], acc[mi][ni]);
  }

  const int lrow4 = (lane >> 4) * 4;
#pragma unroll
  for (int mi = 0; mi < 4; mi++) {
#pragma unroll
    for (int rr2 = 0; rr2 < 4; rr2++) {
      int r = m0 + wr * 64 + mi * 16 + lrow4 + rr2;
      float g0 = 0.f, g2 = 0.f;
      const float* retb = nullptr;
      if (EPI == 2) {
        g0 = gates[2 * r];
        g2 = gates[2 * r + 1];
        retb = ret + ((r >> 11) << 10);
      }
#pragma unroll
      for (int ni = 0; ni < 4; ni++) {
        int c = n0 + wc * 64 + ni * 16 + (lane & 15);
        float v = acc[mi][ni][rr2];
        long idx = (long)r * N + c;
        if (EPI == 0) {
          if (bias) v += bias[c];
          outb[idx] = (bf16_t)v;
        } else if (EPI == 2) {
          outf[idx] = resid[idx] + g0 * (v + bias[c]) + g2 * retb[c];
        } else {
          outf[idx] = resid[idx] + v;
        }
      }
    }
  }
}

// ---------------------------------------------------------------- retrieval projection (tiny)
__global__ __launch_bounds__(256) void retproj_kernel(const float* __restrict__ rc,
                                                      const float* __restrict__ rw,
                                                      float* __restrict__ out) {
  int gw = blockIdx.x * 4 + (threadIdx.x >> 6);  // 0..2047
  int lane = threadIdx.x & 63;
  int b = gw >> 10, n = gw & 1023;
  float v = 0.f;
  for (int k = lane; k < Dn; k += 64) v += rc[b * Dn + k] * rw[(long)n * Dn + k];
#pragma unroll
  for (int off = 32; off > 0; off >>= 1) v += __shfl_down(v, off, 64);
  if (lane == 0) out[gw] = v;
}

// ---------------------------------------------------------------- flash sliding-window attention
__global__ __launch_bounds__(256) void attn_kernel(const bf16_t* __restrict__ qkv,
                                                   bf16_t* __restrict__ out) {
  __shared__ bf16_t psh[4][512];  // per-wave P tile [16][32]
  const int tid = threadIdx.x, w = tid >> 6, lane = tid & 63;
  const int qb = blockIdx.x, bh = blockIdx.y;
  const int b = bh >> 4, h = bh & 15;
  const int qw0 = qb * 64 + w * 16;
  const bf16_t* base = qkv + (long)b * Tn * 3072 + h * 64;
  const bf16_t* kb = base + Dn;
  const bf16_t* vb = base + 2 * Dn;
  const int lr = lane & 15, lg = lane >> 4;

  bf16x8 aq0 = *(const bf16x8*)(base + (long)(qw0 + lr) * 3072 + lg * 8);
  bf16x8 aq1 = *(const bf16x8*)(base + (long)(qw0 + lr) * 3072 + lg * 8 + 32);

  float m_run[4], l_run[4];
  f32x4 accv[4];
#pragma unroll
  for (int r = 0; r < 4; r++) { m_run[r] = -1e30f; l_run[r] = 0.f; }
#pragma unroll
  for (int c = 0; c < 4; c++) accv[c] = (f32x4){0.f, 0.f, 0.f, 0.f};

  int j_lo = qw0 - (Wn - 1);
  if (j_lo < 0) j_lo = 0;
  j_lo &= ~31;
  const int j_hi = qw0 + 15;

  for (int j0 = j_lo; j0 <= j_hi; j0 += 32) {
    f32x4 s[2];
#pragma unroll
    for (int hh = 0; hh < 2; hh++) {
      const bf16_t* kr = kb + (long)(j0 + hh * 16 + lr) * 3072 + lg * 8;
      bf16x8 k0 = *(const bf16x8*)kr;
      bf16x8 k1 = *(const bf16x8*)(kr + 32);
      f32x4 z = (f32x4){0.f, 0.f, 0.f, 0.f};
      z = MFMA16(aq0, k0, z);
      z = MFMA16(aq1, k1, z);
      s[hh] = z;
    }
    float mt[4];
#pragma unroll
    for (int r = 0; r < 4; r++) {
      int q = qw0 + lg * 4 + r;
      int c0 = j0 + lr, c1 = j0 + 16 + lr;
      float s0 = (q >= c0 && (q - c0) < Wn) ? s[0][r] * 0.125f : -1e30f;
      float s1 = (q >= c1 && (q - c1) < Wn) ? s[1][r] * 0.125f : -1e30f;
      s[0][r] = s0;
      s[1][r] = s1;
      mt[r] = fmaxf(s0, s1);
    }
#pragma unroll
    for (int off = 1; off < 16; off <<= 1)
#pragma unroll
      for (int r = 0; r < 4; r++) mt[r] = fmaxf(mt[r], __shfl_xor(mt[r], off, 64));
    float rs[4];
#pragma unroll
    for (int r = 0; r < 4; r++) {
      float nm = fmaxf(m_run[r], mt[r]);
      float alpha = __expf(m_run[r] - nm);
      m_run[r] = nm;
      float p0 = __expf(s[0][r] - nm);
      float p1 = __expf(s[1][r] - nm);
      psh[w][(lg * 4 + r) * 32 + lr] = (bf16_t)p0;
      psh[w][(lg * 4 + r) * 32 + 16 + lr] = (bf16_t)p1;
      rs[r] = p0 + p1;
      l_run[r] *= alpha;
#pragma unroll
      for (int c = 0; c < 4; c++) accv[c][r] *= alpha;
    }
#pragma unroll
    for (int off = 1; off < 16; off <<= 1)
#pragma unroll
      for (int r = 0; r < 4; r++) rs[r] += __shfl_xor(rs[r], off, 64);
#pragma unroll
    for (int r = 0; r < 4; r++) l_run[r] += rs[r];

    bf16x8 ap = *(const bf16x8*)&psh[w][lr * 32 + lg * 8];
#pragma unroll
    for (int c = 0; c < 4; c++) {
      bf16x8 bv;
#pragma unroll
      for (int jj = 0; jj < 8; jj++) bv[jj] = vb[(long)(j0 + lg * 8 + jj) * 3072 + c * 16 + lr];
      accv[c] = MFMA16(ap, bv, accv[c]);
    }
  }
#pragma unroll
  for (int r = 0; r < 4; r++) {
    float inv = 1.0f / l_run[r];
    long orow = ((long)b * Tn + qw0 + lg * 4 + r) * Dn + h * 64;
#pragma unroll
    for (int c = 0; c < 4; c++) out[orow + c * 16 + lr] = (bf16_t)(accv[c][r] * inv);
  }
}

// ---------------------------------------------------------------- SwiGLU activation
__global__ __launch_bounds__(256) void silu_mul_kernel(const bf16_t* __restrict__ gu,
                                                       bf16_t* __restrict__ act) {
  int m = blockIdx.y;
  int j0 = (blockIdx.x * 256 + threadIdx.x) * 8;
  bf16x8 g = *(const bf16x8*)(gu + (long)m * (2 * DFFn) + j0);
  bf16x8 u = *(const bf16x8*)(gu + (long)m * (2 * DFFn) + DFFn + j0);
  bf16x8 o;
#pragma unroll
  for (int i = 0; i < 8; i++) {
    float gf = (float)g[i], uf = (float)u[i];
    float sf = gf / (1.0f + __expf(-gf));
    o[i] = (bf16_t)(sf * uf);
  }
  *(bf16x8*)(act + (long)m * DFFn + j0) = o;
}

// ---------------------------------------------------------------- launch
extern "C" void kernel_launch(void* const* d_in, const int* in_sizes, int n_in, void* d_out,
                              int out_size, void* d_ws, size_t ws_size, hipStream_t stream) {
  const float* x = (const float*)d_in[0];
  const float* rc = (const float*)d_in[1];
  const float* n1w = (const float*)d_in[2];
  const float* qkv_w = (const float*)d_in[3];
  const float* qkv_b = (const float*)d_in[4];
  const float* proj_w = (const float*)d_in[5];
  const float* proj_b = (const float*)d_in[6];
  const float* gate_w = (const float*)d_in[7];
  const float* gate_b = (const float*)d_in[8];
  const float* ret_w = (const float*)d_in[9];
  const float* n2w = (const float*)d_in[10];
  const float* fgw = (const float*)d_in[11];
  const float* fuw = (const float*)d_in[12];
  const float* fdw = (const float*)d_in[13];
  float* out = (float*)d_out;

  char* ws = (char*)d_ws;
  size_t off = 0;
  auto alloc = [&](size_t bytes) {
    char* p = ws + off;
    off += (bytes + 255) & ~(size_t)255;
    return p;
  };
  bf16_t* wqkv = (bf16_t*)alloc(3072l * 1024 * 2);
  bf16_t* wproj = (bf16_t*)alloc(1024l * 1024 * 2);
  bf16_t* wgup = (bf16_t*)alloc(8192l * 1024 * 2);
  bf16_t* wdown = (bf16_t*)alloc(1024l * 4096 * 2);
  bf16_t* h1 = (bf16_t*)alloc((long)Mn * 1024 * 2);
  bf16_t* h2 = (bf16_t*)alloc((long)Mn * 1024 * 2);
  bf16_t* qkvb = (bf16_t*)alloc((long)Mn * 3072 * 2);
  bf16_t* attnb = (bf16_t*)alloc((long)Mn * 1024 * 2);
  bf16_t* gupo = (bf16_t*)alloc((long)Mn * 8192 * 2);
  bf16_t* actb = (bf16_t*)alloc((long)Mn * 4096 * 2);
  float* gates = (float*)alloc((long)Mn * 2 * 4);
  float* retb = (float*)alloc(2048 * 4);
  float* xmid = (float*)alloc((long)Mn * 1024 * 4);

  // weights -> bf16 (gate & up concatenated into one [8192][1024])
  cvt_f32_bf16_kernel<<<3072, 256, 0, stream>>>((const float4*)qkv_w, (bf16x4v*)wqkv, 786432);
  cvt_f32_bf16_kernel<<<1024, 256, 0, stream>>>((const float4*)proj_w, (bf16x4v*)wproj, 262144);
  cvt_f32_bf16_kernel<<<4096, 256, 0, stream>>>((const float4*)fgw, (bf16x4v*)wgup, 1048576);
  cvt_f32_bf16_kernel<<<4096, 256, 0, stream>>>((const float4*)fuw, (bf16x4v*)(wgup + 4194304),
                                                1048576);
  cvt_f32_bf16_kernel<<<4096, 256, 0, stream>>>((const float4*)fdw, (bf16x4v*)wdown, 1048576);

  rmsnorm_kernel<true><<<Mn, 256, 0, stream>>>(x, n1w, h1, gate_w, gate_b, gates);
  gemm256_kernel<<<dim3(12, 16), 512, 0, stream>>>(h1, wqkv, 1024, 3072, qkv_b, qkvb);
  retproj_kernel<<<512, 256, 0, stream>>>(rc, ret_w, retb);
  attn_kernel<<<dim3(32, 32), 256, 0, stream>>>(qkvb, attnb);
  gemm_kernel<2><<<dim3(8, 32), 256, 0, stream>>>(attnb, wproj, 1024, 1024, proj_b, nullptr, xmid,
                                                  gates, retb, x);
  rmsnorm_kernel<false><<<Mn, 256, 0, stream>>>(xmid, n2w, h2, nullptr, nullptr, nullptr);
  gemm256_kernel<<<dim3(32, 16), 512, 0, stream>>>(h2, wgup, 1024, 8192, nullptr, gupo);
  silu_mul_kernel<<<dim3(2, 4096), 256, 0, stream>>>(gupo, actb);
  gemm_kernel<3><<<dim3(8, 32), 256, 0, stream>>>(actb, wdown, 4096, 1024, nullptr, nullptr, out,
                                                  nullptr, nullptr, xmid);
}

// Round 11
// 431.545 us; speedup vs baseline: 1.1468x; 1.1274x over previous
//
#include <hip/hip_runtime.h>
#include <hip/hip_bf16.h>

typedef __bf16 bf16_t;
typedef __bf16 bf16x8 __attribute__((ext_vector_type(8)));
typedef __bf16 bf16x4v __attribute__((ext_vector_type(4)));
typedef float f32x4 __attribute__((ext_vector_type(4)));

static constexpr int Bn = 2, Tn = 2048, Dn = 1024, DFFn = 4096, Hn = 16, HDn = 64, Wn = 512;
static constexpr int Mn = Bn * Tn;  // 4096

#define MFMA16(a, b, c) __builtin_amdgcn_mfma_f32_16x16x32_bf16(a, b, c, 0, 0, 0)

typedef __attribute__((address_space(3))) void lds_void;
typedef const __attribute__((address_space(1))) void gbl_void;

// ---------------------------------------------------------------- cvt f32->bf16
__global__ __launch_bounds__(256) void cvt_f32_bf16_kernel(const float4* __restrict__ src,
                                                           bf16x4v* __restrict__ dst, int n4) {
  int i = blockIdx.x * 256 + threadIdx.x;
  if (i < n4) {
    float4 v = src[i];
    bf16x4v o;
    o[0] = (bf16_t)v.x; o[1] = (bf16_t)v.y; o[2] = (bf16_t)v.z; o[3] = (bf16_t)v.w;
    dst[i] = o;
  }
}

// ---------------------------------------------------------------- block reduce
__device__ __forceinline__ float blockReduceSum(float v, float* sbuf) {
#pragma unroll
  for (int off = 32; off > 0; off >>= 1) v += __shfl_down(v, off, 64);
  int lane = threadIdx.x & 63, wid = threadIdx.x >> 6;
  __syncthreads();
  if (lane == 0) sbuf[wid] = v;
  __syncthreads();
  return sbuf[0] + sbuf[1] + sbuf[2] + sbuf[3];
}

// ---------------------------------------------------------------- RMSNorm (+gate softmax)
template <bool GATE>
__global__ __launch_bounds__(256) void rmsnorm_kernel(const float* __restrict__ x,
                                                      const float* __restrict__ w,
                                                      bf16_t* __restrict__ out,
                                                      const float* __restrict__ gw,
                                                      const float* __restrict__ gb,
                                                      float* __restrict__ gates) {
  __shared__ float sbuf[4];
  int row = blockIdx.x, tid = threadIdx.x;
  const float4* xr = (const float4*)(x + (long)row * Dn);
  float4 v = xr[tid];
  float ss = v.x * v.x + v.y * v.y + v.z * v.z + v.w * v.w;
  ss = blockReduceSum(ss, sbuf);
  float rms = rsqrtf(ss * (1.0f / Dn) + 1e-6f);
  float4 wv = ((const float4*)w)[tid];
  float h0 = v.x * rms * wv.x, h1 = v.y * rms * wv.y;
  float h2 = v.z * rms * wv.z, h3 = v.w * rms * wv.w;
  bf16x4v o;
  o[0] = (bf16_t)h0; o[1] = (bf16_t)h1; o[2] = (bf16_t)h2; o[3] = (bf16_t)h3;
  ((bf16x4v*)(out + (long)row * Dn))[tid] = o;
  if (GATE) {
    float4 g0v = ((const float4*)gw)[tid];
    float4 g2v = ((const float4*)(gw + 2 * Dn))[tid];
    float l0 = h0 * g0v.x + h1 * g0v.y + h2 * g0v.z + h3 * g0v.w;
    float l2 = h0 * g2v.x + h1 * g2v.y + h2 * g2v.z + h3 * g2v.w;
    l0 = blockReduceSum(l0, sbuf);
    l2 = blockReduceSum(l2, sbuf);
    if (tid == 0) {
      l0 += gb[0];
      l2 += gb[2];
      float mx = fmaxf(l0, l2);
      float e0 = __expf(l0 - mx), e2 = __expf(l2 - mx);
      float inv = 1.0f / (e0 + e2);
      gates[2 * row] = e0 * inv;
      gates[2 * row + 1] = e2 * inv;
    }
  }
}

// ---------------------------------------------------------------- 256x256 8-phase GEMM
// (see round-5 notes; verified on HW round 6)
__global__ __launch_bounds__(512, 2) void gemm256_kernel(const bf16_t* __restrict__ Ag,
                                                         const bf16_t* __restrict__ Wt, int K,
                                                         int N, const float* __restrict__ bias,
                                                         bf16_t* __restrict__ outb) {
  __shared__ bf16_t lds2[65536];  // 128 KB
  const int tid = threadIdx.x;
  const int wid = tid >> 6, lane = tid & 63;
  const int wr = wid >> 2, wc = wid & 3;
  const int m0 = blockIdx.y * 256, n0 = blockIdx.x * 256;
  const int lr = lane & 15, lg = lane >> 4;
  const int lterm = (lr * 32 + lg * 8) ^ (((lr >> 3) & 1) << 4);
  const int colsw = (lane & 3) * 8 ^ (((lane >> 5) & 1) << 4);
  const int NT = K >> 6;

  auto stageA = [&](int buf, int half, int t) {
#pragma unroll
    for (int q = 0; q < 2; q++) {
      int s = q * 8 + wid, s_r = s >> 1, s_c = s & 1;
      const bf16_t* src =
          Ag + (long)(m0 + half * 128 + s_r * 16 + (lane >> 2)) * K + (long)t * 64 + s_c * 32 + colsw;
      bf16_t* dst = &lds2[buf * 32768 + (half * 8 + s_r) * 1024 + s_c * 512];
      __builtin_amdgcn_global_load_lds((gbl_void*)src, (lds_void*)dst, 16, 0, 0);
    }
  };
  auto stageB = [&](int buf, int half, int t) {
#pragma unroll
    for (int q = 0; q < 2; q++) {
      int s = q * 8 + wid, s_r = s >> 1, s_c = s & 1;
      const bf16_t* src =
          Wt + (long)(n0 + half * 128 + s_r * 16 + (lane >> 2)) * K + (long)t * 64 + s_c * 32 + colsw;
      bf16_t* dst = &lds2[buf * 32768 + 16384 + (half * 8 + s_r) * 1024 + s_c * 512];
      __builtin_amdgcn_global_load_lds((gbl_void*)src, (lds_void*)dst, 16, 0, 0);
    }
  };

  f32x4 acc[8][4];
#pragma unroll
  for (int i = 0; i < 8; i++)
#pragma unroll
    for (int j = 0; j < 4; j++) acc[i][j] = (f32x4){0.f, 0.f, 0.f, 0.f};

  stageB(0, 0, 0);
  stageB(0, 1, 0);
  stageA(0, 0, 0);
  stageA(0, 1, 0);
  if (NT > 1) {
    stageB(1, 0, 1);
    stageB(1, 1, 1);
    asm volatile("s_waitcnt vmcnt(4)" ::: "memory");
  } else {
    asm volatile("s_waitcnt vmcnt(0)" ::: "memory");
  }
  __builtin_amdgcn_sched_barrier(0);
  __builtin_amdgcn_s_barrier();

#define LDA(mi, ks) (*(const bf16x8*)&lds2[ca + ((wr << 3) + (mi)) * 1024 + (ks)*512 + lterm])
#define LDB(ni, ks) (*(const bf16x8*)&lds2[cb + ((wc << 2) + (ni)) * 1024 + (ks)*512 + lterm])

#define GPHASE(mi0, ...)                                                                  \
  do {                                                                                    \
    bf16x8 a0k0 = LDA(mi0, 0), a0k1 = LDA(mi0, 1);                                        \
    bf16x8 a1k0 = LDA((mi0) + 1, 0), a1k1 = LDA((mi0) + 1, 1);                            \
    __VA_ARGS__;                                                                          \
    __builtin_amdgcn_s_barrier();                                                         \
    asm volatile("s_waitcnt lgkmcnt(0)" ::: "memory");                                    \
    __builtin_amdgcn_sched_barrier(0);                                                    \
    __builtin_amdgcn_s_setprio(1);                                                        \
    _Pragma("unroll") for (int ni = 0; ni < 4; ni++) {                                    \
      acc[mi0][ni] = MFMA16(a0k0, bfr[ni][0], acc[mi0][ni]);                              \
      acc[mi0][ni] = MFMA16(a0k1, bfr[ni][1], acc[mi0][ni]);                              \
      acc[(mi0) + 1][ni] = MFMA16(a1k0, bfr[ni][0], acc[(mi0) + 1][ni]);                  \
      acc[(mi0) + 1][ni] = MFMA16(a1k1, bfr[ni][1], acc[(mi0) + 1][ni]);                  \
    }                                                                                     \
    __builtin_amdgcn_s_setprio(0);                                                        \
    __builtin_amdgcn_s_barrier();                                                         \
  } while (0)

#define GTILE(t, cur)                                                                     \
  do {                                                                                    \
    const int ca = (cur)*32768, cb = ca + 16384;                                          \
    bf16x8 bfr[4][2];                                                                     \
    _Pragma("unroll") for (int ni = 0; ni < 4; ni++) {                                    \
      bfr[ni][0] = LDB(ni, 0);                                                            \
      bfr[ni][1] = LDB(ni, 1);                                                            \
    }                                                                                     \
    GPHASE(0, {                                                                           \
      if ((t) + 1 < NT) {                                                                 \
        stageA(1 - (cur), 0, (t) + 1);                                                    \
        stageA(1 - (cur), 1, (t) + 1);                                                    \
      }                                                                                   \
    });                                                                                   \
    GPHASE(2, {                                                                           \
      if ((t) + 2 < NT) stageB((cur), 0, (t) + 2);                                        \
    });                                                                                   \
    GPHASE(4, {                                                                           \
      if ((t) + 2 < NT) stageB((cur), 1, (t) + 2);                                        \
    });                                                                                   \
    GPHASE(6, {});                                                                        \
    if ((t) + 1 < NT) {                                                                   \
      if ((t) + 2 < NT)                                                                   \
        asm volatile("s_waitcnt vmcnt(4)" ::: "memory");                                  \
      else                                                                                \
        asm volatile("s_waitcnt vmcnt(0)" ::: "memory");                                  \
      __builtin_amdgcn_sched_barrier(0);                                                  \
      __builtin_amdgcn_s_barrier();                                                       \
    }                                                                                     \
  } while (0)

  for (int t = 0; t < NT; t += 2) {
    GTILE(t, 0);
    GTILE(t + 1, 1);
  }

#pragma unroll
  for (int mi = 0; mi < 8; mi++) {
#pragma unroll
    for (int rr = 0; rr < 4; rr++) {
      long r = m0 + wr * 128 + mi * 16 + lg * 4 + rr;
#pragma unroll
      for (int ni = 0; ni < 4; ni++) {
        int c = n0 + wc * 64 + ni * 16 + lr;
        float v = acc[mi][ni][rr];
        if (bias) v += bias[c];
        outb[r * N + c] = (bf16_t)v;
      }
    }
  }
#undef LDA
#undef LDB
#undef GPHASE
#undef GTILE
}

// ---------------------------------------------------------------- 128x128 double-buffered GEMM
// 2-phase pipeline (stage next || compute cur), BK=64, XOR-subtile-swizzled LDS.
// Designed for small grids (1 block/CU): load latency hides under the SAME block's MFMA.
// EPI 2: outf = resid + g0*(acc+bias) + g2*ret   (proj + mix + residual)
// EPI 3: outf = resid + acc              (ffn down + residual)
template <int EPI>
__global__ __launch_bounds__(256) void gemm128_kernel(const bf16_t* __restrict__ A,
                                                      const bf16_t* __restrict__ Wt, int K, int N,
                                                      const float* __restrict__ bias,
                                                      float* __restrict__ outf,
                                                      const float* __restrict__ gates,
                                                      const float* __restrict__ ret,
                                                      const float* __restrict__ resid) {
  __shared__ bf16_t lds[32768];  // 2 bufs x (A[128][64] + B[128][64]) = 64 KB
  const int tid = threadIdx.x, wid = tid >> 6, lane = tid & 63;
  const int wr = wid >> 1, wc = wid & 1;
  const int m0 = blockIdx.y * 128, n0 = blockIdx.x * 128;
  const int lr = lane & 15, lg = lane >> 4;
  const int lterm = (lr * 32 + lg * 8) ^ (((lr >> 3) & 1) << 4);
  const int colsw = (lane & 3) * 8 ^ (((lane >> 5) & 1) << 4);
  const int NT = K >> 6;

  // 32 chunks of 512 els (16B/lane): A chunks 0..15, B chunks 16..31; wave wid stages 8.
  auto stage = [&](int buf, int t) {
#pragma unroll
    for (int q = 0; q < 8; q++) {
      int c = wid * 8 + q;
      int isB = c >> 4;
      int cc = c & 15;
      int s_r = cc >> 1, s_c = cc & 1;
      const bf16_t* base = isB ? Wt + (long)(n0 + s_r * 16 + (lane >> 2)) * K
                               : A + (long)(m0 + s_r * 16 + (lane >> 2)) * K;
      const bf16_t* src = base + (long)t * 64 + s_c * 32 + colsw;
      bf16_t* dst = &lds[buf * 16384 + isB * 8192 + (s_r * 2 + s_c) * 512];
      __builtin_amdgcn_global_load_lds((gbl_void*)src, (lds_void*)dst, 16, 0, 0);
    }
  };

  f32x4 acc[4][4];
#pragma unroll
  for (int i = 0; i < 4; i++)
#pragma unroll
    for (int j = 0; j < 4; j++) acc[i][j] = (f32x4){0.f, 0.f, 0.f, 0.f};

  stage(0, 0);
  __syncthreads();  // vmcnt(0)+barrier: tile 0 ready

  for (int t = 0; t < NT; t++) {
    const int cur = t & 1;
    if (t + 1 < NT) stage(cur ^ 1, t + 1);  // issue next tile; lands during compute
    const int ab = cur * 16384;
#pragma unroll
    for (int ks = 0; ks < 2; ks++) {
      bf16x8 af[4], bfv[4];
#pragma unroll
      for (int mi = 0; mi < 4; mi++)
        af[mi] = *(const bf16x8*)&lds[ab + ((wr * 4 + mi) * 2 + ks) * 512 + lterm];
#pragma unroll
      for (int ni = 0; ni < 4; ni++)
        bfv[ni] = *(const bf16x8*)&lds[ab + 8192 + ((wc * 4 + ni) * 2 + ks) * 512 + lterm];
#pragma unroll
      for (int mi = 0; mi < 4; mi++)
#pragma unroll
        for (int ni = 0; ni < 4; ni++) acc[mi][ni] = MFMA16(af[mi], bfv[ni], acc[mi][ni]);
    }
    if (t + 1 < NT) __syncthreads();  // drains vmcnt(0): next tile ready; WAR-safe swap
  }

  // epilogue: C/D layout col=lane&15, row=(lane>>4)*4+reg
#pragma unroll
  for (int mi = 0; mi < 4; mi++) {
#pragma unroll
    for (int rr2 = 0; rr2 < 4; rr2++) {
      int r = m0 + wr * 64 + mi * 16 + lg * 4 + rr2;
      float g0 = 0.f, g2 = 0.f;
      const float* retb = nullptr;
      if (EPI == 2) {
        g0 = gates[2 * r];
        g2 = gates[2 * r + 1];
        retb = ret + ((r >> 11) << 10);  // b = r / 2048, row of (B,1024)
      }
#pragma unroll
      for (int ni = 0; ni < 4; ni++) {
        int c = n0 + wc * 64 + ni * 16 + lr;
        float v = acc[mi][ni][rr2];
        long idx = (long)r * N + c;
        if (EPI == 2) {
          outf[idx] = resid[idx] + g0 * (v + bias[c]) + g2 * retb[c];
        } else {
          outf[idx] = resid[idx] + v;
        }
      }
    }
  }
}

// ---------------------------------------------------------------- retrieval projection (tiny)
__global__ __launch_bounds__(256) void retproj_kernel(const float* __restrict__ rc,
                                                      const float* __restrict__ rw,
                                                      float* __restrict__ out) {
  int gw = blockIdx.x * 4 + (threadIdx.x >> 6);  // 0..2047
  int lane = threadIdx.x & 63;
  int b = gw >> 10, n = gw & 1023;
  float v = 0.f;
  for (int k = lane; k < Dn; k += 64) v += rc[b * Dn + k] * rw[(long)n * Dn + k];
#pragma unroll
  for (int off = 32; off > 0; off >>= 1) v += __shfl_down(v, off, 64);
  if (lane == 0) out[gw] = v;
}

// ---------------------------------------------------------------- flash sliding-window attention
__global__ __launch_bounds__(256) void attn_kernel(const bf16_t* __restrict__ qkv,
                                                   bf16_t* __restrict__ out) {
  __shared__ bf16_t psh[4][512];  // per-wave P tile [16][32]
  const int tid = threadIdx.x, w = tid >> 6, lane = tid & 63;
  const int qb = blockIdx.x, bh = blockIdx.y;
  const int b = bh >> 4, h = bh & 15;
  const int qw0 = qb * 64 + w * 16;
  const bf16_t* base = qkv + (long)b * Tn * 3072 + h * 64;
  const bf16_t* kb = base + Dn;
  const bf16_t* vb = base + 2 * Dn;
  const int lr = lane & 15, lg = lane >> 4;

  bf16x8 aq0 = *(const bf16x8*)(base + (long)(qw0 + lr) * 3072 + lg * 8);
  bf16x8 aq1 = *(const bf16x8*)(base + (long)(qw0 + lr) * 3072 + lg * 8 + 32);

  float m_run[4], l_run[4];
  f32x4 accv[4];
#pragma unroll
  for (int r = 0; r < 4; r++) { m_run[r] = -1e30f; l_run[r] = 0.f; }
#pragma unroll
  for (int c = 0; c < 4; c++) accv[c] = (f32x4){0.f, 0.f, 0.f, 0.f};

  int j_lo = qw0 - (Wn - 1);
  if (j_lo < 0) j_lo = 0;
  j_lo &= ~31;
  const int j_hi = qw0 + 15;

  for (int j0 = j_lo; j0 <= j_hi; j0 += 32) {
    f32x4 s[2];
#pragma unroll
    for (int hh = 0; hh < 2; hh++) {
      const bf16_t* kr = kb + (long)(j0 + hh * 16 + lr) * 3072 + lg * 8;
      bf16x8 k0 = *(const bf16x8*)kr;
      bf16x8 k1 = *(const bf16x8*)(kr + 32);
      f32x4 z = (f32x4){0.f, 0.f, 0.f, 0.f};
      z = MFMA16(aq0, k0, z);
      z = MFMA16(aq1, k1, z);
      s[hh] = z;
    }
    float mt[4];
#pragma unroll
    for (int r = 0; r < 4; r++) {
      int q = qw0 + lg * 4 + r;
      int c0 = j0 + lr, c1 = j0 + 16 + lr;
      float s0 = (q >= c0 && (q - c0) < Wn) ? s[0][r] * 0.125f : -1e30f;
      float s1 = (q >= c1 && (q - c1) < Wn) ? s[1][r] * 0.125f : -1e30f;
      s[0][r] = s0;
      s[1][r] = s1;
      mt[r] = fmaxf(s0, s1);
    }
#pragma unroll
    for (int off = 1; off < 16; off <<= 1)
#pragma unroll
      for (int r = 0; r < 4; r++) mt[r] = fmaxf(mt[r], __shfl_xor(mt[r], off, 64));
    float rs[4];
#pragma unroll
    for (int r = 0; r < 4; r++) {
      float nm = fmaxf(m_run[r], mt[r]);
      float alpha = __expf(m_run[r] - nm);
      m_run[r] = nm;
      float p0 = __expf(s[0][r] - nm);
      float p1 = __expf(s[1][r] - nm);
      psh[w][(lg * 4 + r) * 32 + lr] = (bf16_t)p0;
      psh[w][(lg * 4 + r) * 32 + 16 + lr] = (bf16_t)p1;
      rs[r] = p0 + p1;
      l_run[r] *= alpha;
#pragma unroll
      for (int c = 0; c < 4; c++) accv[c][r] *= alpha;
    }
#pragma unroll
    for (int off = 1; off < 16; off <<= 1)
#pragma unroll
      for (int r = 0; r < 4; r++) rs[r] += __shfl_xor(rs[r], off, 64);
#pragma unroll
    for (int r = 0; r < 4; r++) l_run[r] += rs[r];

    bf16x8 ap = *(const bf16x8*)&psh[w][lr * 32 + lg * 8];
#pragma unroll
    for (int c = 0; c < 4; c++) {
      bf16x8 bv;
#pragma unroll
      for (int jj = 0; jj < 8; jj++) bv[jj] = vb[(long)(j0 + lg * 8 + jj) * 3072 + c * 16 + lr];
      accv[c] = MFMA16(ap, bv, accv[c]);
    }
  }
#pragma unroll
  for (int r = 0; r < 4; r++) {
    float inv = 1.0f / l_run[r];
    long orow = ((long)b * Tn + qw0 + lg * 4 + r) * Dn + h * 64;
#pragma unroll
    for (int c = 0; c < 4; c++) out[orow + c * 16 + lr] = (bf16_t)(accv[c][r] * inv);
  }
}

// ---------------------------------------------------------------- SwiGLU activation
__global__ __launch_bounds__(256) void silu_mul_kernel(const bf16_t* __restrict__ gu,
                                                       bf16_t* __restrict__ act) {
  int m = blockIdx.y;
  int j0 = (blockIdx.x * 256 + threadIdx.x) * 8;
  bf16x8 g = *(const bf16x8*)(gu + (long)m * (2 * DFFn) + j0);
  bf16x8 u = *(const bf16x8*)(gu + (long)m * (2 * DFFn) + DFFn + j0);
  bf16x8 o;
#pragma unroll
  for (int i = 0; i < 8; i++) {
    float gf = (float)g[i], uf = (float)u[i];
    float sf = gf / (1.0f + __expf(-gf));
    o[i] = (bf16_t)(sf * uf);
  }
  *(bf16x8*)(act + (long)m * DFFn + j0) = o;
}

// ---------------------------------------------------------------- launch
extern "C" void kernel_launch(void* const* d_in, const int* in_sizes, int n_in, void* d_out,
                              int out_size, void* d_ws, size_t ws_size, hipStream_t stream) {
  const float* x = (const float*)d_in[0];
  const float* rc = (const float*)d_in[1];
  const float* n1w = (const float*)d_in[2];
  const float* qkv_w = (const float*)d_in[3];
  const float* qkv_b = (const float*)d_in[4];
  const float* proj_w = (const float*)d_in[5];
  const float* proj_b = (const float*)d_in[6];
  const float* gate_w = (const float*)d_in[7];
  const float* gate_b = (const float*)d_in[8];
  const float* ret_w = (const float*)d_in[9];
  const float* n2w = (const float*)d_in[10];
  const float* fgw = (const float*)d_in[11];
  const float* fuw = (const float*)d_in[12];
  const float* fdw = (const float*)d_in[13];
  float* out = (float*)d_out;

  char* ws = (char*)d_ws;
  size_t off = 0;
  auto alloc = [&](size_t bytes) {
    char* p = ws + off;
    off += (bytes + 255) & ~(size_t)255;
    return p;
  };
  bf16_t* wqkv = (bf16_t*)alloc(3072l * 1024 * 2);
  bf16_t* wproj = (bf16_t*)alloc(1024l * 1024 * 2);
  bf16_t* wgup = (bf16_t*)alloc(8192l * 1024 * 2);
  bf16_t* wdown = (bf16_t*)alloc(1024l * 4096 * 2);
  bf16_t* h1 = (bf16_t*)alloc((long)Mn * 1024 * 2);
  bf16_t* h2 = (bf16_t*)alloc((long)Mn * 1024 * 2);
  bf16_t* qkvb = (bf16_t*)alloc((long)Mn * 3072 * 2);
  bf16_t* attnb = (bf16_t*)alloc((long)Mn * 1024 * 2);
  bf16_t* gupo = (bf16_t*)alloc((long)Mn * 8192 * 2);
  bf16_t* actb = (bf16_t*)alloc((long)Mn * 4096 * 2);
  float* gates = (float*)alloc((long)Mn * 2 * 4);
  float* retb = (float*)alloc(2048 * 4);
  float* xmid = (float*)alloc((long)Mn * 1024 * 4);

  // weights -> bf16 (gate & up concatenated into one [8192][1024])
  cvt_f32_bf16_kernel<<<3072, 256, 0, stream>>>((const float4*)qkv_w, (bf16x4v*)wqkv, 786432);
  cvt_f32_bf16_kernel<<<1024, 256, 0, stream>>>((const float4*)proj_w, (bf16x4v*)wproj, 262144);
  cvt_f32_bf16_kernel<<<4096, 256, 0, stream>>>((const float4*)fgw, (bf16x4v*)wgup, 1048576);
  cvt_f32_bf16_kernel<<<4096, 256, 0, stream>>>((const float4*)fuw, (bf16x4v*)(wgup + 4194304),
                                                1048576);
  cvt_f32_bf16_kernel<<<4096, 256, 0, stream>>>((const float4*)fdw, (bf16x4v*)wdown, 1048576);

  rmsnorm_kernel<true><<<Mn, 256, 0, stream>>>(x, n1w, h1, gate_w, gate_b, gates);
  gemm256_kernel<<<dim3(12, 16), 512, 0, stream>>>(h1, wqkv, 1024, 3072, qkv_b, qkvb);
  retproj_kernel<<<512, 256, 0, stream>>>(rc, ret_w, retb);
  attn_kernel<<<dim3(32, 32), 256, 0, stream>>>(qkvb, attnb);
  gemm128_kernel<2><<<dim3(8, 32), 256, 0, stream>>>(attnb, wproj, 1024, 1024, proj_b, xmid, gates,
                                                     retb, x);
  rmsnorm_kernel<false><<<Mn, 256, 0, stream>>>(xmid, n2w, h2, nullptr, nullptr, nullptr);
  gemm256_kernel<<<dim3(32, 16), 512, 0, stream>>>(h2, wgup, 1024, 8192, nullptr, gupo);
  silu_mul_kernel<<<dim3(2, 4096), 256, 0, stream>>>(gupo, actb);
  gemm128_kernel<3><<<dim3(8, 32), 256, 0, stream>>>(actb, wdown, 4096, 1024, nullptr, out,
                                                     nullptr, nullptr, xmid);
}

// Round 12
// 429.637 us; speedup vs baseline: 1.1519x; 1.0044x over previous
//
#include <hip/hip_runtime.h>
#include <hip/hip_bf16.h>

typedef __bf16 bf16_t;
typedef __bf16 bf16x8 __attribute__((ext_vector_type(8)));
typedef __bf16 bf16x4v __attribute__((ext_vector_type(4)));
typedef float f32x4 __attribute__((ext_vector_type(4)));

static constexpr int Bn = 2, Tn = 2048, Dn = 1024, DFFn = 4096, Hn = 16, HDn = 64, Wn = 512;
static constexpr int Mn = Bn * Tn;  // 4096

#define MFMA16(a, b, c) __builtin_amdgcn_mfma_f32_16x16x32_bf16(a, b, c, 0, 0, 0)

typedef __attribute__((address_space(3))) void lds_void;
typedef const __attribute__((address_space(1))) void gbl_void;

// ---------------------------------------------------------------- cvt f32->bf16
__global__ __launch_bounds__(256) void cvt_f32_bf16_kernel(const float4* __restrict__ src,
                                                           bf16x4v* __restrict__ dst, int n4) {
  int i = blockIdx.x * 256 + threadIdx.x;
  if (i < n4) {
    float4 v = src[i];
    bf16x4v o;
    o[0] = (bf16_t)v.x; o[1] = (bf16_t)v.y; o[2] = (bf16_t)v.z; o[3] = (bf16_t)v.w;
    dst[i] = o;
  }
}

// ---------------------------------------------------------------- cvt + row-interleave gate/up
// dst row 2j = gate row j ; dst row 2j+1 = up row j   (rows of 1024 f32 -> bf16)
__global__ __launch_bounds__(256) void cvt_interleave_kernel(const float4* __restrict__ g,
                                                             const float4* __restrict__ u,
                                                             bf16x4v* __restrict__ dst) {
  int i = blockIdx.x * 256 + threadIdx.x;  // over 4096*256 float4s per matrix
  int j = i >> 8, c4 = i & 255;
  float4 vg = g[i], vu = u[i];
  bf16x4v og, ou;
  og[0] = (bf16_t)vg.x; og[1] = (bf16_t)vg.y; og[2] = (bf16_t)vg.z; og[3] = (bf16_t)vg.w;
  ou[0] = (bf16_t)vu.x; ou[1] = (bf16_t)vu.y; ou[2] = (bf16_t)vu.z; ou[3] = (bf16_t)vu.w;
  dst[(2 * j) * 256 + c4] = og;
  dst[(2 * j + 1) * 256 + c4] = ou;
}

// ---------------------------------------------------------------- block reduce
__device__ __forceinline__ float blockReduceSum(float v, float* sbuf) {
#pragma unroll
  for (int off = 32; off > 0; off >>= 1) v += __shfl_down(v, off, 64);
  int lane = threadIdx.x & 63, wid = threadIdx.x >> 6;
  __syncthreads();
  if (lane == 0) sbuf[wid] = v;
  __syncthreads();
  return sbuf[0] + sbuf[1] + sbuf[2] + sbuf[3];
}

// ---------------------------------------------------------------- RMSNorm (+gate softmax)
template <bool GATE>
__global__ __launch_bounds__(256) void rmsnorm_kernel(const float* __restrict__ x,
                                                      const float* __restrict__ w,
                                                      bf16_t* __restrict__ out,
                                                      const float* __restrict__ gw,
                                                      const float* __restrict__ gb,
                                                      float* __restrict__ gates) {
  __shared__ float sbuf[4];
  int row = blockIdx.x, tid = threadIdx.x;
  const float4* xr = (const float4*)(x + (long)row * Dn);
  float4 v = xr[tid];
  float ss = v.x * v.x + v.y * v.y + v.z * v.z + v.w * v.w;
  ss = blockReduceSum(ss, sbuf);
  float rms = rsqrtf(ss * (1.0f / Dn) + 1e-6f);
  float4 wv = ((const float4*)w)[tid];
  float h0 = v.x * rms * wv.x, h1 = v.y * rms * wv.y;
  float h2 = v.z * rms * wv.z, h3 = v.w * rms * wv.w;
  bf16x4v o;
  o[0] = (bf16_t)h0; o[1] = (bf16_t)h1; o[2] = (bf16_t)h2; o[3] = (bf16_t)h3;
  ((bf16x4v*)(out + (long)row * Dn))[tid] = o;
  if (GATE) {
    float4 g0v = ((const float4*)gw)[tid];
    float4 g2v = ((const float4*)(gw + 2 * Dn))[tid];
    float l0 = h0 * g0v.x + h1 * g0v.y + h2 * g0v.z + h3 * g0v.w;
    float l2 = h0 * g2v.x + h1 * g2v.y + h2 * g2v.z + h3 * g2v.w;
    l0 = blockReduceSum(l0, sbuf);
    l2 = blockReduceSum(l2, sbuf);
    if (tid == 0) {
      l0 += gb[0];
      l2 += gb[2];
      float mx = fmaxf(l0, l2);
      float e0 = __expf(l0 - mx), e2 = __expf(l2 - mx);
      float inv = 1.0f / (e0 + e2);
      gates[2 * row] = e0 * inv;
      gates[2 * row + 1] = e2 * inv;
    }
  }
}

// ---------------------------------------------------------------- 256x256 8-phase GEMM
// (schedule verified on HW rounds 6/11; bank-conflict = 0)
// EPI 0: outb[r*N+c] = bf16(acc + bias?)                      (qkv)
// EPI 1: SwiGLU-fused: B rows interleaved (even=gate,odd=up); even-col lanes
//        write bf16(silu(gate)*up) to outb[r*(N/2) + c/2]     (ffn gate+up)
template <int EPI>
__global__ __launch_bounds__(512, 2) void gemm256_kernel(const bf16_t* __restrict__ Ag,
                                                         const bf16_t* __restrict__ Wt, int K,
                                                         int N, const float* __restrict__ bias,
                                                         bf16_t* __restrict__ outb) {
  __shared__ bf16_t lds2[65536];  // 128 KB
  const int tid = threadIdx.x;
  const int wid = tid >> 6, lane = tid & 63;
  const int wr = wid >> 2, wc = wid & 3;
  const int m0 = blockIdx.y * 256, n0 = blockIdx.x * 256;
  const int lr = lane & 15, lg = lane >> 4;
  const int lterm = (lr * 32 + lg * 8) ^ (((lr >> 3) & 1) << 4);
  const int colsw = (lane & 3) * 8 ^ (((lane >> 5) & 1) << 4);
  const int NT = K >> 6;

  auto stageA = [&](int buf, int half, int t) {
#pragma unroll
    for (int q = 0; q < 2; q++) {
      int s = q * 8 + wid, s_r = s >> 1, s_c = s & 1;
      const bf16_t* src =
          Ag + (long)(m0 + half * 128 + s_r * 16 + (lane >> 2)) * K + (long)t * 64 + s_c * 32 + colsw;
      bf16_t* dst = &lds2[buf * 32768 + (half * 8 + s_r) * 1024 + s_c * 512];
      __builtin_amdgcn_global_load_lds((gbl_void*)src, (lds_void*)dst, 16, 0, 0);
    }
  };
  auto stageB = [&](int buf, int half, int t) {
#pragma unroll
    for (int q = 0; q < 2; q++) {
      int s = q * 8 + wid, s_r = s >> 1, s_c = s & 1;
      const bf16_t* src =
          Wt + (long)(n0 + half * 128 + s_r * 16 + (lane >> 2)) * K + (long)t * 64 + s_c * 32 + colsw;
      bf16_t* dst = &lds2[buf * 32768 + 16384 + (half * 8 + s_r) * 1024 + s_c * 512];
      __builtin_amdgcn_global_load_lds((gbl_void*)src, (lds_void*)dst, 16, 0, 0);
    }
  };

  f32x4 acc[8][4];
#pragma unroll
  for (int i = 0; i < 8; i++)
#pragma unroll
    for (int j = 0; j < 4; j++) acc[i][j] = (f32x4){0.f, 0.f, 0.f, 0.f};

  stageB(0, 0, 0);
  stageB(0, 1, 0);
  stageA(0, 0, 0);
  stageA(0, 1, 0);
  if (NT > 1) {
    stageB(1, 0, 1);
    stageB(1, 1, 1);
    asm volatile("s_waitcnt vmcnt(4)" ::: "memory");
  } else {
    asm volatile("s_waitcnt vmcnt(0)" ::: "memory");
  }
  __builtin_amdgcn_sched_barrier(0);
  __builtin_amdgcn_s_barrier();

#define LDA(mi, ks) (*(const bf16x8*)&lds2[ca + ((wr << 3) + (mi)) * 1024 + (ks)*512 + lterm])
#define LDB(ni, ks) (*(const bf16x8*)&lds2[cb + ((wc << 2) + (ni)) * 1024 + (ks)*512 + lterm])

#define GPHASE(mi0, ...)                                                                  \
  do {                                                                                    \
    bf16x8 a0k0 = LDA(mi0, 0), a0k1 = LDA(mi0, 1);                                        \
    bf16x8 a1k0 = LDA((mi0) + 1, 0), a1k1 = LDA((mi0) + 1, 1);                            \
    __VA_ARGS__;                                                                          \
    __builtin_amdgcn_s_barrier();                                                         \
    asm volatile("s_waitcnt lgkmcnt(0)" ::: "memory");                                    \
    __builtin_amdgcn_sched_barrier(0);                                                    \
    __builtin_amdgcn_s_setprio(1);                                                        \
    _Pragma("unroll") for (int ni = 0; ni < 4; ni++) {                                    \
      acc[mi0][ni] = MFMA16(a0k0, bfr[ni][0], acc[mi0][ni]);                              \
      acc[mi0][ni] = MFMA16(a0k1, bfr[ni][1], acc[mi0][ni]);                              \
      acc[(mi0) + 1][ni] = MFMA16(a1k0, bfr[ni][0], acc[(mi0) + 1][ni]);                  \
      acc[(mi0) + 1][ni] = MFMA16(a1k1, bfr[ni][1], acc[(mi0) + 1][ni]);                  \
    }                                                                                     \
    __builtin_amdgcn_s_setprio(0);                                                        \
    __builtin_amdgcn_s_barrier();                                                         \
  } while (0)

#define GTILE(t, cur)                                                                     \
  do {                                                                                    \
    const int ca = (cur)*32768, cb = ca + 16384;                                          \
    bf16x8 bfr[4][2];                                                                     \
    _Pragma("unroll") for (int ni = 0; ni < 4; ni++) {                                    \
      bfr[ni][0] = LDB(ni, 0);                                                            \
      bfr[ni][1] = LDB(ni, 1);                                                            \
    }                                                                                     \
    GPHASE(0, {                                                                           \
      if ((t) + 1 < NT) {                                                                 \
        stageA(1 - (cur), 0, (t) + 1);                                                    \
        stageA(1 - (cur), 1, (t) + 1);                                                    \
      }                                                                                   \
    });                                                                                   \
    GPHASE(2, {                                                                           \
      if ((t) + 2 < NT) stageB((cur), 0, (t) + 2);                                        \
    });                                                                                   \
    GPHASE(4, {                                                                           \
      if ((t) + 2 < NT) stageB((cur), 1, (t) + 2);                                        \
    });                                                                                   \
    GPHASE(6, {});                                                                        \
    if ((t) + 1 < NT) {                                                                   \
      if ((t) + 2 < NT)                                                                   \
        asm volatile("s_waitcnt vmcnt(4)" ::: "memory");                                  \
      else                                                                                \
        asm volatile("s_waitcnt vmcnt(0)" ::: "memory");                                  \
      __builtin_amdgcn_sched_barrier(0);                                                  \
      __builtin_amdgcn_s_barrier();                                                      \
    }                                                                                     \
  } while (0)

  for (int t = 0; t < NT; t += 2) {
    GTILE(t, 0);
    GTILE(t + 1, 1);
  }

  // epilogue: C/D layout col=lane&15, row=(lane>>4)*4+reg
#pragma unroll
  for (int mi = 0; mi < 8; mi++) {
#pragma unroll
    for (int rr = 0; rr < 4; rr++) {
      long r = m0 + wr * 128 + mi * 16 + lg * 4 + rr;
#pragma unroll
      for (int ni = 0; ni < 4; ni++) {
        int c = n0 + wc * 64 + ni * 16 + lr;
        float v = acc[mi][ni][rr];
        if (EPI == 0) {
          if (bias) v += bias[c];
          outb[r * N + c] = (bf16_t)v;
        } else {
          // interleaved cols: even=gate, odd=up; pair lives in adjacent lanes
          float p = __shfl_xor(v, 1, 64);
          if (!(lr & 1)) {
            float s = v / (1.0f + __expf(-v));  // silu(gate)
            outb[r * (N >> 1) + (c >> 1)] = (bf16_t)(s * p);
          }
        }
      }
    }
  }
#undef LDA
#undef LDB
#undef GPHASE
#undef GTILE
}

// ---------------------------------------------------------------- 128x128 double-buffered GEMM
// (verified on HW round 11)
// EPI 2: outf = resid + g0*(acc+bias) + g2*ret   (proj + mix + residual)
// EPI 3: outf = resid + acc              (ffn down + residual)
template <int EPI>
__global__ __launch_bounds__(256) void gemm128_kernel(const bf16_t* __restrict__ A,
                                                      const bf16_t* __restrict__ Wt, int K, int N,
                                                      const float* __restrict__ bias,
                                                      float* __restrict__ outf,
                                                      const float* __restrict__ gates,
                                                      const float* __restrict__ ret,
                                                      const float* __restrict__ resid) {
  __shared__ bf16_t lds[32768];  // 2 bufs x (A[128][64] + B[128][64]) = 64 KB
  const int tid = threadIdx.x, wid = tid >> 6, lane = tid & 63;
  const int wr = wid >> 1, wc = wid & 1;
  const int m0 = blockIdx.y * 128, n0 = blockIdx.x * 128;
  const int lr = lane & 15, lg = lane >> 4;
  const int lterm = (lr * 32 + lg * 8) ^ (((lr >> 3) & 1) << 4);
  const int colsw = (lane & 3) * 8 ^ (((lane >> 5) & 1) << 4);
  const int NT = K >> 6;

  auto stage = [&](int buf, int t) {
#pragma unroll
    for (int q = 0; q < 8; q++) {
      int c = wid * 8 + q;
      int isB = c >> 4;
      int cc = c & 15;
      int s_r = cc >> 1, s_c = cc & 1;
      const bf16_t* base = isB ? Wt + (long)(n0 + s_r * 16 + (lane >> 2)) * K
                               : A + (long)(m0 + s_r * 16 + (lane >> 2)) * K;
      const bf16_t* src = base + (long)t * 64 + s_c * 32 + colsw;
      bf16_t* dst = &lds[buf * 16384 + isB * 8192 + (s_r * 2 + s_c) * 512];
      __builtin_amdgcn_global_load_lds((gbl_void*)src, (lds_void*)dst, 16, 0, 0);
    }
  };

  f32x4 acc[4][4];
#pragma unroll
  for (int i = 0; i < 4; i++)
#pragma unroll
    for (int j = 0; j < 4; j++) acc[i][j] = (f32x4){0.f, 0.f, 0.f, 0.f};

  stage(0, 0);
  __syncthreads();

  for (int t = 0; t < NT; t++) {
    const int cur = t & 1;
    if (t + 1 < NT) stage(cur ^ 1, t + 1);
    const int ab = cur * 16384;
#pragma unroll
    for (int ks = 0; ks < 2; ks++) {
      bf16x8 af[4], bfv[4];
#pragma unroll
      for (int mi = 0; mi < 4; mi++)
        af[mi] = *(const bf16x8*)&lds[ab + ((wr * 4 + mi) * 2 + ks) * 512 + lterm];
#pragma unroll
      for (int ni = 0; ni < 4; ni++)
        bfv[ni] = *(const bf16x8*)&lds[ab + 8192 + ((wc * 4 + ni) * 2 + ks) * 512 + lterm];
#pragma unroll
      for (int mi = 0; mi < 4; mi++)
#pragma unroll
        for (int ni = 0; ni < 4; ni++) acc[mi][ni] = MFMA16(af[mi], bfv[ni], acc[mi][ni]);
    }
    if (t + 1 < NT) __syncthreads();
  }

#pragma unroll
  for (int mi = 0; mi < 4; mi++) {
#pragma unroll
    for (int rr2 = 0; rr2 < 4; rr2++) {
      int r = m0 + wr * 64 + mi * 16 + lg * 4 + rr2;
      float g0 = 0.f, g2 = 0.f;
      const float* retb = nullptr;
      if (EPI == 2) {
        g0 = gates[2 * r];
        g2 = gates[2 * r + 1];
        retb = ret + ((r >> 11) << 10);
      }
#pragma unroll
      for (int ni = 0; ni < 4; ni++) {
        int c = n0 + wc * 64 + ni * 16 + lr;
        float v = acc[mi][ni][rr2];
        long idx = (long)r * N + c;
        if (EPI == 2) {
          outf[idx] = resid[idx] + g0 * (v + bias[c]) + g2 * retb[c];
        } else {
          outf[idx] = resid[idx] + v;
        }
      }
    }
  }
}

// ---------------------------------------------------------------- retrieval projection (tiny)
__global__ __launch_bounds__(256) void retproj_kernel(const float* __restrict__ rc,
                                                      const float* __restrict__ rw,
                                                      float* __restrict__ out) {
  int gw = blockIdx.x * 4 + (threadIdx.x >> 6);  // 0..2047
  int lane = threadIdx.x & 63;
  int b = gw >> 10, n = gw & 1023;
  float v = 0.f;
  for (int k = lane; k < Dn; k += 64) v += rc[b * Dn + k] * rw[(long)n * Dn + k];
#pragma unroll
  for (int off = 32; off > 0; off >>= 1) v += __shfl_down(v, off, 64);
  if (lane == 0) out[gw] = v;
}

// ---------------------------------------------------------------- flash sliding-window attention
__global__ __launch_bounds__(256) void attn_kernel(const bf16_t* __restrict__ qkv,
                                                   bf16_t* __restrict__ out) {
  __shared__ bf16_t psh[4][512];  // per-wave P tile [16][32]
  const int tid = threadIdx.x, w = tid >> 6, lane = tid & 63;
  const int qb = blockIdx.x, bh = blockIdx.y;
  const int b = bh >> 4, h = bh & 15;
  const int qw0 = qb * 64 + w * 16;
  const bf16_t* base = qkv + (long)b * Tn * 3072 + h * 64;
  const bf16_t* kb = base + Dn;
  const bf16_t* vb = base + 2 * Dn;
  const int lr = lane & 15, lg = lane >> 4;

  bf16x8 aq0 = *(const bf16x8*)(base + (long)(qw0 + lr) * 3072 + lg * 8);
  bf16x8 aq1 = *(const bf16x8*)(base + (long)(qw0 + lr) * 3072 + lg * 8 + 32);

  float m_run[4], l_run[4];
  f32x4 accv[4];
#pragma unroll
  for (int r = 0; r < 4; r++) { m_run[r] = -1e30f; l_run[r] = 0.f; }
#pragma unroll
  for (int c = 0; c < 4; c++) accv[c] = (f32x4){0.f, 0.f, 0.f, 0.f};

  int j_lo = qw0 - (Wn - 1);
  if (j_lo < 0) j_lo = 0;
  j_lo &= ~31;
  const int j_hi = qw0 + 15;

  for (int j0 = j_lo; j0 <= j_hi; j0 += 32) {
    f32x4 s[2];
#pragma unroll
    for (int hh = 0; hh < 2; hh++) {
      const bf16_t* kr = kb + (long)(j0 + hh * 16 + lr) * 3072 + lg * 8;
      bf16x8 k0 = *(const bf16x8*)kr;
      bf16x8 k1 = *(const bf16x8*)(kr + 32);
      f32x4 z = (f32x4){0.f, 0.f, 0.f, 0.f};
      z = MFMA16(aq0, k0, z);
      z = MFMA16(aq1, k1, z);
      s[hh] = z;
    }
    float mt[4];
#pragma unroll
    for (int r = 0; r < 4; r++) {
      int q = qw0 + lg * 4 + r;
      int c0 = j0 + lr, c1 = j0 + 16 + lr;
      float s0 = (q >= c0 && (q - c0) < Wn) ? s[0][r] * 0.125f : -1e30f;
      float s1 = (q >= c1 && (q - c1) < Wn) ? s[1][r] * 0.125f : -1e30f;
      s[0][r] = s0;
      s[1][r] = s1;
      mt[r] = fmaxf(s0, s1);
    }
#pragma unroll
    for (int off = 1; off < 16; off <<= 1)
#pragma unroll
      for (int r = 0; r < 4; r++) mt[r] = fmaxf(mt[r], __shfl_xor(mt[r], off, 64));
    float rs[4];
#pragma unroll
    for (int r = 0; r < 4; r++) {
      float nm = fmaxf(m_run[r], mt[r]);
      float alpha = __expf(m_run[r] - nm);
      m_run[r] = nm;
      float p0 = __expf(s[0][r] - nm);
      float p1 = __expf(s[1][r] - nm);
      psh[w][(lg * 4 + r) * 32 + lr] = (bf16_t)p0;
      psh[w][(lg * 4 + r) * 32 + 16 + lr] = (bf16_t)p1;
      rs[r] = p0 + p1;
      l_run[r] *= alpha;
#pragma unroll
      for (int c = 0; c < 4; c++) accv[c][r] *= alpha;
    }
#pragma unroll
    for (int off = 1; off < 16; off <<= 1)
#pragma unroll
      for (int r = 0; r < 4; r++) rs[r] += __shfl_xor(rs[r], off, 64);
#pragma unroll
    for (int r = 0; r < 4; r++) l_run[r] += rs[r];

    bf16x8 ap = *(const bf16x8*)&psh[w][lr * 32 + lg * 8];
#pragma unroll
    for (int c = 0; c < 4; c++) {
      bf16x8 bv;
#pragma unroll
      for (int jj = 0; jj < 8; jj++) bv[jj] = vb[(long)(j0 + lg * 8 + jj) * 3072 + c * 16 + lr];
      accv[c] = MFMA16(ap, bv, accv[c]);
    }
  }
#pragma unroll
  for (int r = 0; r < 4; r++) {
    float inv = 1.0f / l_run[r];
    long orow = ((long)b * Tn + qw0 + lg * 4 + r) * Dn + h * 64;
#pragma unroll
    for (int c = 0; c < 4; c++) out[orow + c * 16 + lr] = (bf16_t)(accv[c][r] * inv);
  }
}

// ---------------------------------------------------------------- launch
extern "C" void kernel_launch(void* const* d_in, const int* in_sizes, int n_in, void* d_out,
                              int out_size, void* d_ws, size_t ws_size, hipStream_t stream) {
  const float* x = (const float*)d_in[0];
  const float* rc = (const float*)d_in[1];
  const float* n1w = (const float*)d_in[2];
  const float* qkv_w = (const float*)d_in[3];
  const float* qkv_b = (const float*)d_in[4];
  const float* proj_w = (const float*)d_in[5];
  const float* proj_b = (const float*)d_in[6];
  const float* gate_w = (const float*)d_in[7];
  const float* gate_b = (const float*)d_in[8];
  const float* ret_w = (const float*)d_in[9];
  const float* n2w = (const float*)d_in[10];
  const float* fgw = (const float*)d_in[11];
  const float* fuw = (const float*)d_in[12];
  const float* fdw = (const float*)d_in[13];
  float* out = (float*)d_out;

  char* ws = (char*)d_ws;
  size_t off = 0;
  auto alloc = [&](size_t bytes) {
    char* p = ws + off;
    off += (bytes + 255) & ~(size_t)255;
    return p;
  };
  bf16_t* wqkv = (bf16_t*)alloc(3072l * 1024 * 2);
  bf16_t* wproj = (bf16_t*)alloc(1024l * 1024 * 2);
  bf16_t* wgup = (bf16_t*)alloc(8192l * 1024 * 2);  // interleaved gate/up rows
  bf16_t* wdown = (bf16_t*)alloc(1024l * 4096 * 2);
  bf16_t* h1 = (bf16_t*)alloc((long)Mn * 1024 * 2);
  bf16_t* h2 = (bf16_t*)alloc((long)Mn * 1024 * 2);
  bf16_t* qkvb = (bf16_t*)alloc((long)Mn * 3072 * 2);
  bf16_t* attnb = (bf16_t*)alloc((long)Mn * 1024 * 2);
  bf16_t* actb = (bf16_t*)alloc((long)Mn * 4096 * 2);
  float* gates = (float*)alloc((long)Mn * 2 * 4);
  float* retb = (float*)alloc(2048 * 4);
  float* xmid = (float*)alloc((long)Mn * 1024 * 4);

  cvt_f32_bf16_kernel<<<3072, 256, 0, stream>>>((const float4*)qkv_w, (bf16x4v*)wqkv, 786432);
  cvt_f32_bf16_kernel<<<1024, 256, 0, stream>>>((const float4*)proj_w, (bf16x4v*)wproj, 262144);
  cvt_interleave_kernel<<<4096, 256, 0, stream>>>((const float4*)fgw, (const float4*)fuw,
                                                  (bf16x4v*)wgup);
  cvt_f32_bf16_kernel<<<4096, 256, 0, stream>>>((const float4*)fdw, (bf16x4v*)wdown, 1048576);

  rmsnorm_kernel<true><<<Mn, 256, 0, stream>>>(x, n1w, h1, gate_w, gate_b, gates);
  gemm256_kernel<0><<<dim3(12, 16), 512, 0, stream>>>(h1, wqkv, 1024, 3072, qkv_b, qkvb);
  retproj_kernel<<<512, 256, 0, stream>>>(rc, ret_w, retb);
  attn_kernel<<<dim3(32, 32), 256, 0, stream>>>(qkvb, attnb);
  gemm128_kernel<2><<<dim3(8, 32), 256, 0, stream>>>(attnb, wproj, 1024, 1024, proj_b, xmid, gates,
                                                     retb, x);
  rmsnorm_kernel<false><<<Mn, 256, 0, stream>>>(xmid, n2w, h2, nullptr, nullptr, nullptr);
  gemm256_kernel<1><<<dim3(32, 16), 512, 0, stream>>>(h2, wgup, 1024, 8192, nullptr, actb);
  gemm128_kernel<3><<<dim3(8, 32), 256, 0, stream>>>(actb, wdown, 4096, 1024, nullptr, out,
                                                     nullptr, nullptr, xmid);
}